// Round 9
// baseline (130.263 us; speedup 1.0000x reference)
//
#include <hip/hip_runtime.h>
#include <math.h>

#define DIM 4096
#define NH 32
#define NKV 8
#define HD 128
#define NREP 4
#define ABLK 512   // positions per score block (8 waves, 1 t/thread)
#define BBLK 256   // positions per pv block (4 waves, 64 t/wave)

#define LD4(p) (*(const float4*)(p))

// ---------------------------------------------------------------------------
// Kernel 1: q/k/v GEMV + fused RoPE (unchanged).
// ---------------------------------------------------------------------------
__global__ __launch_bounds__(256) void qkv_rope_kernel(
    const float* __restrict__ x, const float* __restrict__ fc,
    const float* __restrict__ fs, const float* __restrict__ wq,
    const float* __restrict__ wk, const float* __restrict__ wv,
    float* __restrict__ q_rope, float* __restrict__ k_new,
    float* __restrict__ v_new) {
  int wave = blockIdx.x * 4 + (threadIdx.x >> 6);
  int lane = threadIdx.x & 63;
  const float* W;
  float* dst;
  int r0;
  bool rope;
  if (wave < 2048) {
    W = wq; dst = q_rope; r0 = wave * 2; rope = true;
  } else if (wave < 2560) {
    W = wk; dst = k_new; r0 = (wave - 2048) * 2; rope = true;
  } else {
    W = wv; dst = v_new; r0 = (wave - 2560) * 2; rope = false;
  }
  const float4* x4 = (const float4*)x;
  const float4* w0 = (const float4*)(W + (size_t)r0 * DIM);
  const float4* w1 = (const float4*)(W + (size_t)(r0 + 1) * DIM);
  float a0 = 0.f, a1 = 0.f;
#pragma unroll 4
  for (int c = lane; c < DIM / 4; c += 64) {
    float4 xv = x4[c];
    float4 u = w0[c];
    float4 v = w1[c];
    a0 += xv.x * u.x + xv.y * u.y + xv.z * u.z + xv.w * u.w;
    a1 += xv.x * v.x + xv.y * v.y + xv.z * v.z + xv.w * v.w;
  }
  for (int off = 32; off > 0; off >>= 1) {
    a0 += __shfl_down(a0, off, 64);
    a1 += __shfl_down(a1, off, 64);
  }
  if (lane == 0) {
    if (rope) {
      int jj = (r0 & (HD - 1)) >> 1;
      float c = fc[jj], s = fs[jj];
      dst[r0]     = a0 * c - a1 * s;
      dst[r0 + 1] = a0 * s + a1 * c;
    } else {
      dst[r0]     = a0;
      dst[r0 + 1] = a1;
    }
  }
}

// ---------------------------------------------------------------------------
// Kernel A: scores + exp. One THREAD owns one position t: streams the
// 512B K-row in 16B chunks (lane stride 4KB -> 64 independent cache lines
// per instruction), dots against block-uniform q (constant-cached), exp with
// m=0 reference (validated R4-R7), writes p4 coalesced. No cross-lane ops
// in the loop.
// ---------------------------------------------------------------------------
__global__ __launch_bounds__(512, 4) void score_kernel(
    const float* __restrict__ q_rope, const float* __restrict__ k_cache,
    float* __restrict__ p_buf, float* __restrict__ partial_l,
    int start_pos, int nsplit_a, int Tpad) {
  int g = blockIdx.x & 7;
  int blk = blockIdx.x >> 3;
  int tid = threadIdx.x;
  int t = blk * ABLK + tid;
  bool valid = t < start_pos;
  int tc = valid ? t : 0;
  const float* kr = k_cache + ((size_t)tc * NKV + g) * HD;
  const float* qb = q_rope + (size_t)(g * NREP) * HD;  // block-uniform
  float s0 = 0.f, s1 = 0.f, s2 = 0.f, s3 = 0.f;
#pragma unroll 4
  for (int c = 0; c < 8; ++c) {
#pragma unroll
    for (int u = 0; u < 4; ++u) {
      int o = c * 16 + u * 4;
      float4 K4 = LD4(kr + o);
      float4 q0 = LD4(qb + 0 * HD + o);
      float4 q1 = LD4(qb + 1 * HD + o);
      float4 q2 = LD4(qb + 2 * HD + o);
      float4 q3 = LD4(qb + 3 * HD + o);
      s0 += K4.x * q0.x + K4.y * q0.y + K4.z * q0.z + K4.w * q0.w;
      s1 += K4.x * q1.x + K4.y * q1.y + K4.z * q1.z + K4.w * q1.w;
      s2 += K4.x * q2.x + K4.y * q2.y + K4.z * q2.z + K4.w * q2.w;
      s3 += K4.x * q3.x + K4.y * q3.y + K4.z * q3.z + K4.w * q3.w;
    }
  }
  const float scale = 0.08838834764831845f;  // 1/sqrt(128)
  float p0 = valid ? __expf(s0 * scale) : 0.f;
  float p1 = valid ? __expf(s1 * scale) : 0.f;
  float p2 = valid ? __expf(s2 * scale) : 0.f;
  float p3 = valid ? __expf(s3 * scale) : 0.f;
  float4 pv4;
  pv4.x = p0; pv4.y = p1; pv4.z = p2; pv4.w = p3;
  *(float4*)&p_buf[((size_t)g * Tpad + t) * 4] = pv4;

  // block lsum: wave butterfly (once) + LDS combine
  float l0 = p0, l1 = p1, l2 = p2, l3 = p3;
#pragma unroll
  for (int m = 1; m <= 32; m <<= 1) {
    l0 += __shfl_xor(l0, m, 64);
    l1 += __shfl_xor(l1, m, 64);
    l2 += __shfl_xor(l2, m, 64);
    l3 += __shfl_xor(l3, m, 64);
  }
  __shared__ float sl[8][4];
  int w = tid >> 6, l = tid & 63;
  if (l == 0) {
    sl[w][0] = l0; sl[w][1] = l1; sl[w][2] = l2; sl[w][3] = l3;
  }
  __syncthreads();
  if (tid < NREP) {
    float L = 0.f;
#pragma unroll
    for (int ww = 0; ww < 8; ++ww) L += sl[ww][tid];
    partial_l[(g * NREP + tid) * nsplit_a + blk] = L;
  }
}

// ---------------------------------------------------------------------------
// Kernel B: PV. Lane = (head h=l>>4, d-slot ds=l&15). Per t: 2 coalesced
// V float4 loads + 1 broadcast p scalar + 16 FMA into registers. No
// cross-lane ops; one LDS cross-wave combine at block end.
// ---------------------------------------------------------------------------
__global__ __launch_bounds__(256, 4) void pv_kernel(
    const float* __restrict__ p_buf, const float* __restrict__ v_cache,
    float* __restrict__ partial_o, int start_pos, int nsplit_b, int Tpad) {
  int g = blockIdx.x & 7;
  int split = blockIdx.x >> 3;
  int tid = threadIdx.x;
  int w = tid >> 6, l = tid & 63;
  int h = l >> 4, ds = l & 15;
  int tb = split * BBLK + w * 64;
  const float* pb = p_buf + ((size_t)g * Tpad + tb) * 4 + h;
  float out[8] = {0.f, 0.f, 0.f, 0.f, 0.f, 0.f, 0.f, 0.f};
#pragma unroll 4
  for (int i = 0; i < 64; ++i) {
    int t = tb + i;
    int tcl = t < start_pos ? t : start_pos - 1;  // safe addr; p=0 if invalid
    float p = pb[i * 4];
    const float* vr = v_cache + ((size_t)tcl * NKV + g) * HD + ds * 8;
    float4 Va = LD4(vr);
    float4 Vb = LD4(vr + 4);
    out[0] += p * Va.x; out[1] += p * Va.y;
    out[2] += p * Va.z; out[3] += p * Va.w;
    out[4] += p * Vb.x; out[5] += p * Vb.y;
    out[6] += p * Vb.z; out[7] += p * Vb.w;
  }
  __shared__ float sacc[4][NREP][HD];
  float4 oa, ob;
  oa.x = out[0]; oa.y = out[1]; oa.z = out[2]; oa.w = out[3];
  ob.x = out[4]; ob.y = out[5]; ob.z = out[6]; ob.w = out[7];
  *(float4*)&sacc[w][h][ds * 8] = oa;
  *(float4*)&sacc[w][h][ds * 8 + 4] = ob;
  __syncthreads();
  for (int idx = tid; idx < NREP * HD; idx += 256) {
    int hh = idx >> 7, d = idx & (HD - 1);
    float s = sacc[0][hh][d] + sacc[1][hh][d] + sacc[2][hh][d] +
              sacc[3][hh][d];
    partial_o[((size_t)(g * NREP + hh) * nsplit_b + split) * HD + d] = s;
  }
}

// ---------------------------------------------------------------------------
// Kernel 3: combine splits + new-token contribution (m=0 everywhere).
// ---------------------------------------------------------------------------
__global__ __launch_bounds__(128) void combine_kernel(
    const float* __restrict__ q_rope, const float* __restrict__ k_new,
    const float* __restrict__ v_new, const float* __restrict__ partial_l,
    const float* __restrict__ partial_o, float* __restrict__ attn_out,
    int nsplit_a, int nsplit_b) {
  int hh = blockIdx.x;
  int g = hh >> 2;
  int tid = threadIdx.x;
  __shared__ float sp[128];
  sp[tid] = q_rope[hh * HD + tid] * k_new[g * HD + tid];
  __syncthreads();
  for (int s = 64; s > 0; s >>= 1) {
    if (tid < s) sp[tid] += sp[tid + s];
    __syncthreads();
  }
  float e_new = __expf(sp[0] * 0.08838834764831845f);
  float L = e_new;
  for (int s = 0; s < nsplit_a; ++s) L += partial_l[hh * nsplit_a + s];
  float acc = e_new * v_new[g * HD + tid];
#pragma unroll 4
  for (int s = 0; s < nsplit_b; ++s)
    acc += partial_o[((size_t)hh * nsplit_b + s) * HD + tid];
  attn_out[hh * HD + tid] = acc / L;
}

// ---------------------------------------------------------------------------
// Kernel 4: out = attn @ wo.T (unchanged).
// ---------------------------------------------------------------------------
__global__ __launch_bounds__(256) void out_gemv_kernel(
    const float* __restrict__ attn, const float* __restrict__ wo,
    float* __restrict__ out) {
  int row = blockIdx.x * 4 + (threadIdx.x >> 6);
  int lane = threadIdx.x & 63;
  const float4* a4 = (const float4*)attn;
  const float4* w4 = (const float4*)(wo + (size_t)row * DIM);
  float a = 0.f;
#pragma unroll 4
  for (int c = lane; c < DIM / 4; c += 64) {
    float4 av = a4[c];
    float4 wv = w4[c];
    a += av.x * wv.x + av.y * wv.y + av.z * wv.z + av.w * wv.w;
  }
  for (int off = 32; off > 0; off >>= 1) a += __shfl_down(a, off, 64);
  if (lane == 0) out[row] = a;
}

extern "C" void kernel_launch(void* const* d_in, const int* in_sizes, int n_in,
                              void* d_out, int out_size, void* d_ws,
                              size_t ws_size, hipStream_t stream) {
  const float* x       = (const float*)d_in[0];
  const float* fc      = (const float*)d_in[1];
  const float* fs      = (const float*)d_in[2];
  const float* k_cache = (const float*)d_in[3];
  const float* v_cache = (const float*)d_in[4];
  const float* wq      = (const float*)d_in[5];
  const float* wk      = (const float*)d_in[6];
  const float* wv      = (const float*)d_in[7];
  const float* wo      = (const float*)d_in[8];
  float* out = (float*)d_out;

  int start_pos = in_sizes[3] / (NKV * HD);  // cache length (32767)
  int nsplit_a = (start_pos + ABLK - 1) / ABLK;   // 64
  int Tpad = nsplit_a * ABLK;                     // 32768
  int nsplit_b = Tpad / BBLK;                     // 128

  float* ws = (float*)d_ws;
  float* q_rope    = ws;                               // 4096
  float* k_new     = ws + 4096;                        // 1024
  float* v_new     = ws + 5120;                        // 1024
  float* attn_out  = ws + 6144;                        // 4096
  float* partial_l = ws + 10240;                       // NH*nsplit_a
  float* partial_o = partial_l + NH * nsplit_a;        // NH*nsplit_b*HD
  float* p_buf     = partial_o + (size_t)NH * nsplit_b * HD;  // 8*Tpad*4

  qkv_rope_kernel<<<768, 256, 0, stream>>>(x, fc, fs, wq, wk, wv, q_rope,
                                           k_new, v_new);
  score_kernel<<<8 * nsplit_a, ABLK, 0, stream>>>(
      q_rope, k_cache, p_buf, partial_l, start_pos, nsplit_a, Tpad);
  pv_kernel<<<8 * nsplit_b, BBLK, 0, stream>>>(
      p_buf, v_cache, partial_o, start_pos, nsplit_b, Tpad);
  combine_kernel<<<NH, 128, 0, stream>>>(q_rope, k_new, v_new, partial_l,
                                         partial_o, attn_out, nsplit_a,
                                         nsplit_b);
  out_gemv_kernel<<<1024, 256, 0, stream>>>(attn_out, wo, out);
}